// Round 9
// baseline (272.554 us; speedup 1.0000x reference)
//
#include <hip/hip_runtime.h>

typedef short bf16x8 __attribute__((ext_vector_type(8)));
typedef float f32x4 __attribute__((ext_vector_type(4)));
typedef unsigned short ushort8 __attribute__((ext_vector_type(8)));
typedef unsigned short ushort4v __attribute__((ext_vector_type(4)));

#define BATCH 16
#define DCAT 512
#define CIN 256
#define COUT 256
#define HH 64
#define WW 64
#define HP 66
#define WP 66
#define PLANE (HP * WP * 8)  // shorts per c8-plane
#define AHALO 52224          // 408 entries (6 rows x 68 cols) * 128B
#define BBUF 32768

__device__ __forceinline__ unsigned short f2bf(float f) {
  unsigned int u = __float_as_uint(f);
  unsigned int r = (u + 0x7fffu + ((u >> 16) & 1u)) >> 16;
  return (unsigned short)r;
}

// ---------------- MLP layer: one wave per output element (b,c).
template <int IN_DIM>
__global__ void __launch_bounds__(256) mlp_layer(const float* __restrict__ in,
                                                 const float* __restrict__ w,
                                                 const float* __restrict__ bias,
                                                 float* __restrict__ out) {
  int wid = threadIdx.x >> 6, lane = threadIdx.x & 63;
  int oidx = blockIdx.x * 4 + wid;  // (b<<8)|c
  int b = oidx >> 8, c = oidx & 255;
  const float* wr = w + (size_t)c * IN_DIM;
  const float* ir = in + (size_t)b * IN_DIM;
  float sum = 0.f;
#pragma unroll
  for (int d0 = 0; d0 < IN_DIM; d0 += 256) {
    f32x4 wv = *(const f32x4*)(wr + d0 + lane * 4);
    f32x4 iv = *(const f32x4*)(ir + d0 + lane * 4);
    sum += wv[0] * iv[0] + wv[1] * iv[1] + wv[2] * iv[2] + wv[3] * iv[3];
  }
#pragma unroll
  for (int off = 32; off; off >>= 1) sum += __shfl_xor(sum, off, 64);
  if (lane == 0) {
    float a = sum + bias[c];
    out[oidx] = a >= 0.f ? a : 0.01f * a;
  }
}

// ---------------- consolidated prep (tap-major wt): R0-verbatim.
__global__ void __launch_bounds__(256) prep_all(const float* __restrict__ t1,
                                                const float* __restrict__ w2,
                                                const float* __restrict__ b2,
                                                const float* __restrict__ x,
                                                const float* __restrict__ cw,
                                                unsigned short* __restrict__ xpad,
                                                unsigned short* __restrict__ wt) {
  int blk = blockIdx.x;
  int tid = threadIdx.x;

  if (blk >= 1024) {  // ---- prep_w part
    int idx = (blk - 1024) * 256 + tid;  // 9*256*64 = 147456 threads
    int t = idx / 16384;
    int r = idx - t * 16384;  // o*64 + i4
    int o = r >> 6, i4 = r & 63;
    ushort4v v;
#pragma unroll
    for (int j = 0; j < 4; j++) v[j] = f2bf(cw[(o * 256 + i4 * 4 + j) * 9 + t]);
    *(ushort4v*)(wt + ((size_t)(t * COUT + o)) * CIN + i4 * 4) = v;
    return;
  }

  // ---- prep_x part: blk = (b<<6) | (c8<<1) | h
  int h = blk & 1, c8 = (blk >> 1) & 31, b = blk >> 6;
  int wid = tid >> 6, lane = tid & 63;

  float tv = t1[b * CIN + tid];
  float pj[8];
#pragma unroll
  for (int j = 0; j < 8; j++) pj[j] = w2[(size_t)(c8 * 8 + j) * CIN + tid] * tv;

  const float* xb = x + ((size_t)(b * CIN + c8 * 8)) * (HH * WW);
  int gg0 = h * 512 + tid;
  int gg1 = gg0 + 256;
  int hh0 = (gg0 >> 4) + 1, w00 = (gg0 & 15) * 4 + 1;
  int hh1 = (gg1 >> 4) + 1, w01 = (gg1 & 15) * 4 + 1;
  int base0 = (hh0 - 1) * WW + (w00 - 1);
  int base1 = (hh1 - 1) * WW + (w01 - 1);
  f32x4 v0[8], v1[8];
#pragma unroll
  for (int j = 0; j < 8; j++) v0[j] = *(const f32x4*)(xb + j * (HH * WW) + base0);
#pragma unroll
  for (int j = 0; j < 8; j++) v1[j] = *(const f32x4*)(xb + j * (HH * WW) + base1);

#pragma unroll
  for (int off = 32; off; off >>= 1)
#pragma unroll
    for (int j = 0; j < 8; j++) pj[j] += __shfl_xor(pj[j], off, 64);
  __shared__ float red[4][8];
  __shared__ float sv_sh[8];
  if (lane == 0)
#pragma unroll
    for (int j = 0; j < 8; j++) red[wid][j] = pj[j];
  __syncthreads();
  if (tid < 8) {
    float a = red[0][tid] + red[1][tid] + red[2][tid] + red[3][tid] + b2[c8 * 8 + tid];
    sv_sh[tid] = a >= 0.f ? a : 0.01f * a;
  }
  __syncthreads();
  float sv[8];
#pragma unroll
  for (int j = 0; j < 8; j++) sv[j] = sv_sh[j];

  unsigned short* xp = xpad + ((size_t)(b * 32 + c8)) * PLANE;

  if (tid < 130) {
    int i = h * 130 + tid;
    int bh, bw;
    if (i < 66) { bh = 0; bw = i; }
    else if (i < 132) { bh = 65; bw = i - 66; }
    else if (i < 196) { bh = i - 132 + 1; bw = 0; }
    else { bh = i - 196 + 1; bw = 65; }
    ushort8 z = {0, 0, 0, 0, 0, 0, 0, 0};
    *(ushort8*)(xp + (bh * WP + bw) * 8) = z;
  }

  unsigned short* op0 = xp + (hh0 * WP + w00) * 8;
  unsigned short* op1 = xp + (hh1 * WP + w01) * 8;
#pragma unroll
  for (int t2 = 0; t2 < 4; t2++) {
    ushort8 o;
#pragma unroll
    for (int j = 0; j < 8; j++) o[j] = f2bf(v0[j][t2] * sv[j]);
    *(ushort8*)(op0 + t2 * 8) = o;
  }
#pragma unroll
  for (int t2 = 0; t2 < 4; t2++) {
    ushort8 o;
#pragma unroll
    for (int j = 0; j < 8; j++) o[j] = f2bf(v1[j][t2] * sv[j]);
    *(ushort8*)(op1 + t2 * 8) = o;
  }
}

// ---------------- implicit-GEMM conv, R9: tap-reuse + 4-wave 128x128 tiles.
// 256 threads = 4 waves (2x2), 1 wave/SIMD -> 512 unified regs/wave:
// acc[8][8] (256 AGPR) + both kb operand sets (128 VGPR) fit WITHOUT spill.
// Halved LDS-read traffic vs 8-wave (128 reads/CU/tap vs 192): A-dup 2x,
// B-dup 2x. kb1 reads issued before kb0's MFMA cluster; compiler's partial
// lgkmcnt overlaps their drain with kb0 compute. B double-buffered, staged
// every tap with full-tap cover; A halo staged once per kc2.
__device__ __forceinline__ void gl2lds16(const void* g, void* l) {
  __builtin_amdgcn_global_load_lds((const __attribute__((address_space(1))) void*)g,
                                   (__attribute__((address_space(3))) void*)l, 16, 0, 0);
}

__global__ void __launch_bounds__(256, 1) gemm_conv(const unsigned short* __restrict__ xpad,
                                                    const unsigned short* __restrict__ wt,
                                                    float* __restrict__ out) {
  // LDS: A halo [0, 52224), B buf0 [52224, +32K), B buf1 [84992, +32K)
  __shared__ __align__(16) char lds[AHALO + 2 * BBUF];
  int tid = threadIdx.x;
  int wid = tid >> 6, lane = tid & 63;
  int bid = blockIdx.x;
  // XCD swizzle: 256 blocks, 32 contiguous tiles (=2 images) per XCD.
  int m_t = (bid & 7) * 32 + (bid >> 3);
  int m0 = m_t << 8;                 // first pixel of tile (BM=256 = 4 image rows)
  int b = m0 >> 12;
  int h0 = (m0 >> 6) & 63;           // tile covers image rows h0..h0+3
  int wm = wid & 1, wn = wid >> 1;   // 2x2 wave grid, wave tile 128px x 128o

  f32x4 acc[8][8];
#pragma unroll
  for (int mi = 0; mi < 8; mi++)
#pragma unroll
    for (int ni = 0; ni < 8; ni++) acc[mi][ni] = (f32x4){0.f, 0.f, 0.f, 0.f};

  // ---- B stager invariants: lane covers o row o_l(+q*64/+32), chunk csb.
  int o_l = tid >> 3;                // 0..31
  int csb = tid & 7;
  const unsigned short* bL = wt + o_l * CIN + ((csb ^ (o_l & 7)) * 8);

#define STAGE_B(BUF, BG)                                                \
  do {                                                                  \
    char* dB = lds + AHALO + (BUF) * BBUF + wid * 1024;                 \
    _Pragma("unroll")                                                   \
    for (int q = 0; q < 4; q++) {                                       \
      gl2lds16((BG) + q * 64 * CIN, dB + q * 8192);                     \
      gl2lds16((BG) + q * 64 * CIN + 32 * CIN, dB + q * 8192 + 4096);   \
    }                                                                   \
  } while (0)

  // ---- reader invariants
  int qa = lane >> 4;
  int l15 = lane & 15;
  int offB0 = (wn * 128 + l15) * 128 + ((qa ^ (l15 & 7)) * 16);
  int offB1 = (wn * 128 + l15) * 128 + (((qa + 4) ^ (l15 & 7)) * 16);

  int cur = 0;
  for (int kc2 = 0; kc2 < 4; kc2++) {
    // ---- stage A halo for this kc2 (once): 51 chunk-rows of 1 KB, 4 waves.
    // chunk-group g: entries e = g*8 + lane>>3, slot csb holds chunk csb^(e&7).
    size_t kofs = (size_t)kc2 * 8 * PLANE;  // shorts: +8 c8-planes
#pragma unroll
    for (int i = 0; i < 13; i++) {
      int g = i * 4 + wid;
      if (i < 12 || wid < 3) {
        int e = g * 8 + (lane >> 3);
        int gs = csb ^ (e & 7);
        int rh = e / 68;
        int wc = e - rh * 68;
        const unsigned short* src =
            xpad + ((size_t)((b * 32 + gs) * HP + (h0 + rh))) * (WP * 8) + wc * 8 + kofs;
        gl2lds16(src, lds + g * 1024);
      }
    }
    if (kc2 == 0) STAGE_B(0, bL);      // tap-0 B; later kc2s staged it at tap 8
    __syncthreads();  // drains vmcnt(0): A halo (+B0) resident

    for (int kh = 0; kh < 3; kh++) {
      for (int kw = 0; kw < 3; kw++) {
        int tap = kh * 3 + kw;
        // issue next B stage (next tap, or next kc2's tap 0) into buf cur^1
        if (tap < 8 || kc2 < 3) {
          const unsigned short* bG = (tap < 8)
              ? bL + (tap + 1) * (COUT * CIN) + kc2 * 64
              : bL + (kc2 + 1) * 64;
          STAGE_B(cur ^ 1, bG);
        }

        // A window offsets for this tap (XOR-swizzle re-based: 68 ≡ 4 mod 8)
        int eb = (wm * 2 + kh) * 68 + l15 + kw;
        int s0 = eb & 7, s1 = (eb + 4) & 7;
        int a00 = eb * 128 + ((qa ^ s0) * 16);
        int a01 = (eb + 68) * 128 + ((qa ^ s1) * 16);
        int a10 = eb * 128 + (((qa + 4) ^ s0) * 16);
        int a11 = (eb + 68) * 128 + (((qa + 4) ^ s1) * 16);
        const char* Bb = lds + AHALO + cur * BBUF;

        // kb0 reads (16) then kb1 reads (16): kb0 cluster waits only on its
        // own reads (partial lgkmcnt); kb1's drain under kb0's 64 MFMAs.
        bf16x8 av[8], bv0[8], aw[8], bv1[8];
#pragma unroll
        for (int mi = 0; mi < 4; mi++) {
          av[mi] = *(const bf16x8*)(lds + a00 + mi * 2048);
          av[4 + mi] = *(const bf16x8*)(lds + a01 + mi * 2048);
        }
#pragma unroll
        for (int ni = 0; ni < 8; ni++)
          bv0[ni] = *(const bf16x8*)(Bb + offB0 + ni * 2048);
#pragma unroll
        for (int mi = 0; mi < 4; mi++) {
          aw[mi] = *(const bf16x8*)(lds + a10 + mi * 2048);
          aw[4 + mi] = *(const bf16x8*)(lds + a11 + mi * 2048);
        }
#pragma unroll
        for (int ni = 0; ni < 8; ni++)
          bv1[ni] = *(const bf16x8*)(Bb + offB1 + ni * 2048);

        __builtin_amdgcn_s_setprio(1);
#pragma unroll
        for (int mi = 0; mi < 8; mi++)
#pragma unroll
          for (int ni = 0; ni < 8; ni++)
            acc[mi][ni] = __builtin_amdgcn_mfma_f32_16x16x32_bf16(av[mi], bv0[ni],
                                                                  acc[mi][ni], 0, 0, 0);
#pragma unroll
        for (int mi = 0; mi < 8; mi++)
#pragma unroll
          for (int ni = 0; ni < 8; ni++)
            acc[mi][ni] = __builtin_amdgcn_mfma_f32_16x16x32_bf16(aw[mi], bv1[ni],
                                                                  acc[mi][ni], 0, 0, 0);
        __builtin_amdgcn_s_setprio(0);

        __syncthreads();  // implicit vmcnt(0): next-B landed under MFMA cover
        cur ^= 1;
      }
    }
  }

  // ---- epilogue: D row = pixel (quad*4+reg), col = o (lane&15)
  int pixbase = m0 & 4095;
  int quad = lane >> 4;
  int col = lane & 15;
#pragma unroll
  for (int mi = 0; mi < 8; mi++) {
    int pm = pixbase + wm * 128 + mi * 16 + quad * 4;
#pragma unroll
    for (int ni = 0; ni < 8; ni++) {
      int on = wn * 128 + ni * 16 + col;
      float* op = out + ((size_t)(b * COUT + on) << 12) + pm;
      *(f32x4*)op = acc[mi][ni];
    }
  }
}

extern "C" void kernel_launch(void* const* d_in, const int* in_sizes, int n_in,
                              void* d_out, int out_size, void* d_ws, size_t ws_size,
                              hipStream_t stream) {
  const float* x = (const float*)d_in[0];
  const float* y = (const float*)d_in[1];
  const float* w0 = (const float*)d_in[2];
  const float* b0 = (const float*)d_in[3];
  const float* w1 = (const float*)d_in[4];
  const float* b1 = (const float*)d_in[5];
  const float* w2 = (const float*)d_in[6];
  const float* b2 = (const float*)d_in[7];
  const float* cw = (const float*)d_in[8];
  float* out = (float*)d_out;

  // xpad FIRST so the A-halo's 16-32B tail over-read lands in wt, inside ws.
  char* ws = (char*)d_ws;
  unsigned short* xpad = (unsigned short*)ws;                   // 35,684,352 B
  unsigned short* wt = (unsigned short*)(ws + 35684352);        // 2,359,296 B
  float* t0 = (float*)(ws + 35684352 + 2359296);                // 16 KiB
  float* t1 = (float*)(ws + 35684352 + 2359296 + 16384);        // 16 KiB

  mlp_layer<DCAT><<<BATCH * CIN / 4, 256, 0, stream>>>(y, w0, b0, t0);
  mlp_layer<CIN><<<BATCH * CIN / 4, 256, 0, stream>>>(t0, w1, b1, t1);
  prep_all<<<1024 + 576, 256, 0, stream>>>(t1, w2, b2, x, cw, xpad, wt);
  gemm_conv<<<BATCH * HH * WW / 256, 256, 0, stream>>>(xpad, wt, out);
}

// Round 10
// 213.146 us; speedup vs baseline: 1.2787x; 1.2787x over previous
//
#include <hip/hip_runtime.h>

typedef short bf16x8 __attribute__((ext_vector_type(8)));
typedef float f32x4 __attribute__((ext_vector_type(4)));
typedef unsigned short ushort8 __attribute__((ext_vector_type(8)));
typedef unsigned short ushort4v __attribute__((ext_vector_type(4)));

#define BATCH 16
#define DCAT 512
#define CIN 256
#define COUT 256
#define HH 64
#define WW 64
#define HP 66
#define WP 66
#define PLANE (HP * WP * 8)  // shorts per c8-plane
#define ABUF 26624           // 26 lines of 1KB (408 entries x 64B) + pad
#define BBASE (2 * ABUF)     // per-wave B dbuf region: 8 waves x 2 x 4KB

__device__ __forceinline__ unsigned short f2bf(float f) {
  unsigned int u = __float_as_uint(f);
  unsigned int r = (u + 0x7fffu + ((u >> 16) & 1u)) >> 16;
  return (unsigned short)r;
}

// ---------------- MLP layer: one wave per output element (b,c).
template <int IN_DIM>
__global__ void __launch_bounds__(256) mlp_layer(const float* __restrict__ in,
                                                 const float* __restrict__ w,
                                                 const float* __restrict__ bias,
                                                 float* __restrict__ out) {
  int wid = threadIdx.x >> 6, lane = threadIdx.x & 63;
  int oidx = blockIdx.x * 4 + wid;  // (b<<8)|c
  int b = oidx >> 8, c = oidx & 255;
  const float* wr = w + (size_t)c * IN_DIM;
  const float* ir = in + (size_t)b * IN_DIM;
  float sum = 0.f;
#pragma unroll
  for (int d0 = 0; d0 < IN_DIM; d0 += 256) {
    f32x4 wv = *(const f32x4*)(wr + d0 + lane * 4);
    f32x4 iv = *(const f32x4*)(ir + d0 + lane * 4);
    sum += wv[0] * iv[0] + wv[1] * iv[1] + wv[2] * iv[2] + wv[3] * iv[3];
  }
#pragma unroll
  for (int off = 32; off; off >>= 1) sum += __shfl_xor(sum, off, 64);
  if (lane == 0) {
    float a = sum + bias[c];
    out[oidx] = a >= 0.f ? a : 0.01f * a;
  }
}

// ---------------- consolidated prep (tap-major wt): R0-verbatim.
__global__ void __launch_bounds__(256) prep_all(const float* __restrict__ t1,
                                                const float* __restrict__ w2,
                                                const float* __restrict__ b2,
                                                const float* __restrict__ x,
                                                const float* __restrict__ cw,
                                                unsigned short* __restrict__ xpad,
                                                unsigned short* __restrict__ wt) {
  int blk = blockIdx.x;
  int tid = threadIdx.x;

  if (blk >= 1024) {  // ---- prep_w part
    int idx = (blk - 1024) * 256 + tid;  // 9*256*64 = 147456 threads
    int t = idx / 16384;
    int r = idx - t * 16384;  // o*64 + i4
    int o = r >> 6, i4 = r & 63;
    ushort4v v;
#pragma unroll
    for (int j = 0; j < 4; j++) v[j] = f2bf(cw[(o * 256 + i4 * 4 + j) * 9 + t]);
    *(ushort4v*)(wt + ((size_t)(t * COUT + o)) * CIN + i4 * 4) = v;
    return;
  }

  // ---- prep_x part: blk = (b<<6) | (c8<<1) | h
  int h = blk & 1, c8 = (blk >> 1) & 31, b = blk >> 6;
  int wid = tid >> 6, lane = tid & 63;

  float tv = t1[b * CIN + tid];
  float pj[8];
#pragma unroll
  for (int j = 0; j < 8; j++) pj[j] = w2[(size_t)(c8 * 8 + j) * CIN + tid] * tv;

  const float* xb = x + ((size_t)(b * CIN + c8 * 8)) * (HH * WW);
  int gg0 = h * 512 + tid;
  int gg1 = gg0 + 256;
  int hh0 = (gg0 >> 4) + 1, w00 = (gg0 & 15) * 4 + 1;
  int hh1 = (gg1 >> 4) + 1, w01 = (gg1 & 15) * 4 + 1;
  int base0 = (hh0 - 1) * WW + (w00 - 1);
  int base1 = (hh1 - 1) * WW + (w01 - 1);
  f32x4 v0[8], v1[8];
#pragma unroll
  for (int j = 0; j < 8; j++) v0[j] = *(const f32x4*)(xb + j * (HH * WW) + base0);
#pragma unroll
  for (int j = 0; j < 8; j++) v1[j] = *(const f32x4*)(xb + j * (HH * WW) + base1);

#pragma unroll
  for (int off = 32; off; off >>= 1)
#pragma unroll
    for (int j = 0; j < 8; j++) pj[j] += __shfl_xor(pj[j], off, 64);
  __shared__ float red[4][8];
  __shared__ float sv_sh[8];
  if (lane == 0)
#pragma unroll
    for (int j = 0; j < 8; j++) red[wid][j] = pj[j];
  __syncthreads();
  if (tid < 8) {
    float a = red[0][tid] + red[1][tid] + red[2][tid] + red[3][tid] + b2[c8 * 8 + tid];
    sv_sh[tid] = a >= 0.f ? a : 0.01f * a;
  }
  __syncthreads();
  float sv[8];
#pragma unroll
  for (int j = 0; j < 8; j++) sv[j] = sv_sh[j];

  unsigned short* xp = xpad + ((size_t)(b * 32 + c8)) * PLANE;

  if (tid < 130) {
    int i = h * 130 + tid;
    int bh, bw;
    if (i < 66) { bh = 0; bw = i; }
    else if (i < 132) { bh = 65; bw = i - 66; }
    else if (i < 196) { bh = i - 132 + 1; bw = 0; }
    else { bh = i - 196 + 1; bw = 65; }
    ushort8 z = {0, 0, 0, 0, 0, 0, 0, 0};
    *(ushort8*)(xp + (bh * WP + bw) * 8) = z;
  }

  unsigned short* op0 = xp + (hh0 * WP + w00) * 8;
  unsigned short* op1 = xp + (hh1 * WP + w01) * 8;
#pragma unroll
  for (int t2 = 0; t2 < 4; t2++) {
    ushort8 o;
#pragma unroll
    for (int j = 0; j < 8; j++) o[j] = f2bf(v0[j][t2] * sv[j]);
    *(ushort8*)(op0 + t2 * 8) = o;
  }
#pragma unroll
  for (int t2 = 0; t2 < 4; t2++) {
    ushort8 o;
#pragma unroll
    for (int j = 0; j < 8; j++) o[j] = f2bf(v1[j][t2] * sv[j]);
    *(ushort8*)(op1 + t2 * 8) = o;
  }
}

// ---------------- implicit-GEMM conv R10: barrier-free taps.
// 8 slices of 32ch. A halo (26KB/slice) double-buffered, staged cooperatively,
// 1 barrier per slice. B: per-wave private dbuf (4KB x2 x8 waves) staged by
// global_load_lds and synchronized with the OWN wave's vmcnt only -> taps
// have NO barrier; the 2 waves/SIMD drift so ds_read phases of one overlap
// MFMA phases of the other. Per wave per tap: 12 ds_read_b128 + 32 MFMA.
// LDS 64B entries, swizzle slot = qa ^ ((e>>1)&3) (8-bank spread, 2-way).
__device__ __forceinline__ void gl2lds16(const void* g, void* l) {
  __builtin_amdgcn_global_load_lds((const __attribute__((address_space(1))) void*)g,
                                   (__attribute__((address_space(3))) void*)l, 16, 0, 0);
}

__global__ void __launch_bounds__(512, 1) gemm_conv(const unsigned short* __restrict__ xpad,
                                                    const unsigned short* __restrict__ wt,
                                                    float* __restrict__ out) {
  // LDS: A halo buf0 [0,26624), buf1 [26624,53248), B [53248,118784): wave w
  // at BBASE + w*8192, dbuf halves +0/+4096.
  __shared__ __align__(16) char lds[BBASE + 8 * 8192];
  int tid = threadIdx.x;
  int wid = tid >> 6, lane = tid & 63;
  int bid = blockIdx.x;
  // XCD swizzle: 256 blocks, 32 contiguous tiles (=2 images) per XCD.
  int m_t = (bid & 7) * 32 + (bid >> 3);
  int m0 = m_t << 8;                 // first pixel of tile (BM=256 = 4 image rows)
  int b = m0 >> 12;
  int h0 = (m0 >> 6) & 63;           // tile covers image rows h0..h0+3
  int wm = wid & 1, wn = wid >> 1;   // 2x4 wave grid, wave tile 128px x 64o

  f32x4 acc[8][4];
#pragma unroll
  for (int mi = 0; mi < 8; mi++)
#pragma unroll
    for (int ni = 0; ni < 4; ni++) acc[mi][ni] = (f32x4){0.f, 0.f, 0.f, 0.f};

  // ---- A halo stager: line L = wid + i*8 (i<4, L<26). Lane l covers entry
  // e = L*16 + (l>>2), slot cs = l&3 holding chunk gs = cs ^ ((e>>1)&3)
  // = (l&3) ^ ((l>>3)&3). Base for slice 0; +slice*4*PLANE per slice.
  const unsigned short* aSrc[4];
  {
    int gsA = (lane & 3) ^ ((lane >> 3) & 3);
#pragma unroll
    for (int i = 0; i < 4; i++) {
      int L = wid + i * 8;
      int e = L * 16 + (lane >> 2);
      int rh = e / 68, wc = e - rh * 68;
      aSrc[i] = xpad + ((size_t)((b * 32 + gsA) * HP + (h0 + rh))) * (WP * 8) + wc * 8;
    }
  }

  // ---- B stager (own wave): line g covers rows g*16+(l>>2) of the wave's 64
  // o-rows; chunk slot l&3 holds gs = (l&3)^((l>>3)&3). +g*16*CIN per line.
  const unsigned short* bS0 =
      wt + (size_t)(wn * 64 + (lane >> 2)) * CIN + ((lane & 3) ^ ((lane >> 3) & 3)) * 8;
  char* myB = lds + BBASE + wid * 8192;

  // ---- reader invariants
  int qa = lane >> 4;
  int l15 = lane & 15;
  int obr = l15 * 64 + ((qa ^ ((l15 >> 1) & 3)) * 16);  // B frag, +ni*1024

#define STAGE_B(BUF, SRC)                                        \
  do {                                                           \
    char* dB_ = myB + (BUF) * 4096;                              \
    const unsigned short* s_ = (SRC);                            \
    _Pragma("unroll")                                            \
    for (int g = 0; g < 4; g++)                                  \
      gl2lds16(s_ + g * 16 * CIN, dB_ + g * 1024);               \
  } while (0)

#define STAGE_A(SL)                                              \
  do {                                                           \
    size_t ao_ = (size_t)(SL) * 4 * PLANE;                       \
    char* dA_ = lds + ((SL) & 1) * ABUF;                         \
    _Pragma("unroll")                                            \
    for (int i = 0; i < 4; i++) {                                \
      int L_ = wid + i * 8;                                      \
      if (L_ < 26) gl2lds16(aSrc[i] + ao_, dA_ + L_ * 1024);     \
    }                                                            \
  } while (0)

  // ---- prologue: A slice 0 + own B (slice 0, tap 0) into buf 0
  STAGE_A(0);
  STAGE_B(0, bS0);
  asm volatile("s_waitcnt vmcnt(0)" ::: "memory");
  __builtin_amdgcn_s_barrier();

  int bcur = 0;
  for (int slice = 0; slice < 8; slice++) {
    const char* Ac = lds + (slice & 1) * ABUF;
    for (int kh = 0; kh < 3; kh++) {
      for (int kw = 0; kw < 3; kw++) {
        int t = kh * 3 + kw;
        // ---- stage next B (own wave): next tap, or next slice's tap 0
        if (t < 8) {
          STAGE_B(bcur ^ 1, bS0 + (size_t)(t + 1) * (COUT * CIN) + slice * 32);
        } else if (slice < 7) {
          STAGE_B(bcur ^ 1, bS0 + (slice + 1) * 32);
        }
        // ---- tap 7: stage next slice's A halo (2 taps of cover)
        if (t == 7 && slice < 7) STAGE_A(slice + 1);

        // ---- own-wave wait: B(t) resident. No barrier.
        if (t < 8) {
          asm volatile("s_waitcnt vmcnt(4)" ::: "memory");
        } else if (slice < 7) {
          asm volatile("s_waitcnt vmcnt(7)" ::: "memory");
        } else {
          asm volatile("s_waitcnt vmcnt(0)" ::: "memory");
        }

        // ---- A window offsets (64B entries; slot = qa ^ ((e>>1)&3))
        int eb = (wm * 2 + kh) * 68 + l15 + kw;
        int e2 = eb + 68;
        int a0 = eb * 64 + ((qa ^ ((eb >> 1) & 3)) * 16);
        int a1 = e2 * 64 + ((qa ^ ((e2 >> 1) & 3)) * 16);
        const char* Bb = myB + bcur * 4096;

        bf16x8 av[8], bv[4];
#pragma unroll
        for (int mi = 0; mi < 4; mi++) {
          av[mi] = *(const bf16x8*)(Ac + a0 + mi * 1024);
          av[4 + mi] = *(const bf16x8*)(Ac + a1 + mi * 1024);
        }
#pragma unroll
        for (int ni = 0; ni < 4; ni++)
          bv[ni] = *(const bf16x8*)(Bb + obr + ni * 1024);

        __builtin_amdgcn_s_setprio(1);
#pragma unroll
        for (int mi = 0; mi < 8; mi++)
#pragma unroll
          for (int ni = 0; ni < 4; ni++)
            acc[mi][ni] = __builtin_amdgcn_mfma_f32_16x16x32_bf16(av[mi], bv[ni],
                                                                  acc[mi][ni], 0, 0, 0);
        __builtin_amdgcn_s_setprio(0);

        // ---- slice end: drain own A loads, then the one barrier per slice
        if (t == 8 && slice < 7) {
          asm volatile("s_waitcnt vmcnt(0)" ::: "memory");
          __builtin_amdgcn_s_barrier();
        }
        bcur ^= 1;
      }
    }
  }

  // ---- epilogue (R7-verbatim): D row = pixel (quad*4+reg), col = o (lane&15)
  int pixbase = m0 & 4095;
  int quad = lane >> 4;
  int col = lane & 15;
#pragma unroll
  for (int mi = 0; mi < 8; mi++) {
    int pm = pixbase + wm * 128 + mi * 16 + quad * 4;
#pragma unroll
    for (int ni = 0; ni < 4; ni++) {
      int on = wn * 64 + ni * 16 + col;
      float* op = out + ((size_t)(b * COUT + on) << 12) + pm;
      *(f32x4*)op = acc[mi][ni];
    }
  }
}

extern "C" void kernel_launch(void* const* d_in, const int* in_sizes, int n_in,
                              void* d_out, int out_size, void* d_ws, size_t ws_size,
                              hipStream_t stream) {
  const float* x = (const float*)d_in[0];
  const float* y = (const float*)d_in[1];
  const float* w0 = (const float*)d_in[2];
  const float* b0 = (const float*)d_in[3];
  const float* w1 = (const float*)d_in[4];
  const float* b1 = (const float*)d_in[5];
  const float* w2 = (const float*)d_in[6];
  const float* b2 = (const float*)d_in[7];
  const float* cw = (const float*)d_in[8];
  float* out = (float*)d_out;

  // xpad FIRST so the A-halo tail over-read lands in wt, inside ws.
  char* ws = (char*)d_ws;
  unsigned short* xpad = (unsigned short*)ws;                   // 35,684,352 B
  unsigned short* wt = (unsigned short*)(ws + 35684352);        // 2,359,296 B
  float* t0 = (float*)(ws + 35684352 + 2359296);                // 16 KiB
  float* t1 = (float*)(ws + 35684352 + 2359296 + 16384);        // 16 KiB

  mlp_layer<DCAT><<<BATCH * CIN / 4, 256, 0, stream>>>(y, w0, b0, t0);
  mlp_layer<CIN><<<BATCH * CIN / 4, 256, 0, stream>>>(t0, w1, b1, t1);
  prep_all<<<1024 + 576, 256, 0, stream>>>(t1, w2, b2, x, cw, xpad, wt);
  gemm_conv<<<BATCH * HH * WW / 256, 512, 0, stream>>>(xpad, wt, out);
}